// Round 1
// baseline (407.755 us; speedup 1.0000x reference)
//
#include <hip/hip_runtime.h>
#include <hip/hip_bf16.h>

// Problem: B=4, S=2048, D=1024, H=16, HD=64, causal MHA forward, fp32 in/out.
// Strategy: bf16 MFMA for all matmuls (threshold 2.77e-2 permits), 5 kernels:
//   1-3) Q/K/V projection GEMMs (fp32 in -> bf16 out in attention layouts)
//   4)   flash attention (online softmax), bf16 out [B,S,D]
//   5)   output projection GEMM (bf16 in -> fp32 out + bias)

#define SLEN 2048
#define DMOD 1024

typedef __attribute__((ext_vector_type(8))) short s16x8;   // 8 bf16 (4 VGPRs)
typedef __attribute__((ext_vector_type(4))) float f32x4;

__device__ __forceinline__ unsigned short f2bf(float f) {
    union { float f; unsigned u; } v; v.f = f;
    unsigned r = v.u + 0x7fffu + ((v.u >> 16) & 1u);   // RNE
    return (unsigned short)(r >> 16);
}

// ---------------- projection GEMM: Y = X @ W^T + bias ----------------
// X: [8192,1024] (fp32 if !ABF, bf16-ushort if ABF), W: [1024,1024] fp32 ([e][d] = B^T form)
// MODE 0: bf16 out at [B,H,S,HD]   (for Q, K)
// MODE 1: bf16 out at [B,H,HD,S]   (for V, pre-transposed for PV fragment loads)
// MODE 2: fp32 out at [B,S,D]      (final projection -> d_out)
template<int MODE, bool ABF>
__global__ __launch_bounds__(256) void proj_gemm(
    const void* __restrict__ Aptr, const float* __restrict__ W,
    const float* __restrict__ bias, void* __restrict__ outp)
{
    __shared__ unsigned short Asm[128][72];   // +8 pad: row stride 144B (16B-aligned, 2-way banks)
    __shared__ unsigned short Bsm[128][72];
    const int tid  = threadIdx.x;
    const int lane = tid & 63, wid = tid >> 6;
    const int l15 = lane & 15, lhi = lane >> 4;
    const int m0 = blockIdx.y * 128, n0 = blockIdx.x * 128;
    const int wr = wid >> 1, wc = wid & 1;   // 2x2 wave grid, each wave 64x64

    f32x4 acc[4][4];
#pragma unroll
    for (int i = 0; i < 4; ++i)
#pragma unroll
        for (int j = 0; j < 4; ++j) acc[i][j] = (f32x4)0.f;

    for (int k0 = 0; k0 < 1024; k0 += 64) {
        // --- stage A tile (128x64) ---
        if constexpr (ABF) {
            const unsigned short* A = (const unsigned short*)Aptr;
#pragma unroll
            for (int p = 0; p < 4; ++p) {
                int idx = p * 256 + tid;
                int row = idx >> 3, c8 = (idx & 7) * 8;
                *reinterpret_cast<int4*>(&Asm[row][c8]) =
                    *reinterpret_cast<const int4*>(&A[(size_t)(m0 + row) * 1024 + k0 + c8]);
            }
        } else {
            const float* A = (const float*)Aptr;
#pragma unroll
            for (int p = 0; p < 8; ++p) {
                int idx = p * 256 + tid;
                int row = idx >> 4, c4 = (idx & 15) * 4;
                float4 v = *reinterpret_cast<const float4*>(&A[(size_t)(m0 + row) * 1024 + k0 + c4]);
                uint2 u;
                u.x = (unsigned)f2bf(v.x) | ((unsigned)f2bf(v.y) << 16);
                u.y = (unsigned)f2bf(v.z) | ((unsigned)f2bf(v.w) << 16);
                *reinterpret_cast<uint2*>(&Asm[row][c4]) = u;
            }
        }
        // --- stage B tile (W rows n0..n0+127, 64 k-cols) ---
        {
#pragma unroll
            for (int p = 0; p < 8; ++p) {
                int idx = p * 256 + tid;
                int row = idx >> 4, c4 = (idx & 15) * 4;
                float4 v = *reinterpret_cast<const float4*>(&W[(size_t)(n0 + row) * 1024 + k0 + c4]);
                uint2 u;
                u.x = (unsigned)f2bf(v.x) | ((unsigned)f2bf(v.y) << 16);
                u.y = (unsigned)f2bf(v.z) | ((unsigned)f2bf(v.w) << 16);
                *reinterpret_cast<uint2*>(&Bsm[row][c4]) = u;
            }
        }
        __syncthreads();
#pragma unroll
        for (int kk = 0; kk < 2; ++kk) {
            const int kc = kk * 32 + 8 * lhi;
            s16x8 af[4], bfv[4];
#pragma unroll
            for (int i = 0; i < 4; ++i)
                af[i] = *reinterpret_cast<const s16x8*>(&Asm[wr * 64 + i * 16 + l15][kc]);
#pragma unroll
            for (int j = 0; j < 4; ++j)
                bfv[j] = *reinterpret_cast<const s16x8*>(&Bsm[wc * 64 + j * 16 + l15][kc]);
#pragma unroll
            for (int i = 0; i < 4; ++i)
#pragma unroll
                for (int j = 0; j < 4; ++j)
                    acc[i][j] = __builtin_amdgcn_mfma_f32_16x16x32_bf16(af[i], bfv[j], acc[i][j], 0, 0, 0);
        }
        __syncthreads();
    }

    // --- epilogue: C/D layout col=lane&15, row=(lane>>4)*4+reg (m89-verified) ---
#pragma unroll
    for (int j = 0; j < 4; ++j) {
        const int col = n0 + wc * 64 + j * 16 + l15;
        const float bv = bias[col];
#pragma unroll
        for (int i = 0; i < 4; ++i) {
#pragma unroll
            for (int r = 0; r < 4; ++r) {
                const int row = m0 + wr * 64 + i * 16 + lhi * 4 + r;
                const float val = acc[i][j][r] + bv;
                if constexpr (MODE == 2) {
                    ((float*)outp)[(size_t)row * 1024 + col] = val;
                } else if constexpr (MODE == 0) {
                    // [B,H,S,HD]: ((b*16+h)*2048 + s)*64 + hd
                    ((unsigned short*)outp)[(size_t)((row >> 11) * 16 + (col >> 6)) * 131072
                                            + (size_t)(row & 2047) * 64 + (col & 63)] = f2bf(val);
                } else {
                    // [B,H,HD,S]: ((b*16+h)*64 + hd)*2048 + s
                    ((unsigned short*)outp)[(size_t)((row >> 11) * 16 + (col >> 6)) * 131072
                                            + (size_t)(col & 63) * 2048 + (row & 2047)] = f2bf(val);
                }
            }
        }
    }
}

// ---------------- flash attention ----------------
// Q,K: [B*H, S, 64] bf16.  Vt: [B*H, 64, S] bf16.  Ao: [B,S,D] bf16.
// grid (S/64, B*H), 256 threads = 4 waves, each wave owns 16 q-rows.
__global__ __launch_bounds__(256) void attn_kernel(
    const unsigned short* __restrict__ Q,
    const unsigned short* __restrict__ Kc,
    const unsigned short* __restrict__ Vt,
    unsigned short* __restrict__ Ao)
{
    __shared__ unsigned short Ksm[64][72];
    __shared__ unsigned short Vsm[64][72];       // V^T tile: [d][kv]
    __shared__ unsigned short Psm[4][16][72];    // per-wave P buffer

    const int tid = threadIdx.x, lane = tid & 63, wid = tid >> 6;
    const int l15 = lane & 15, lhi = lane >> 4;
    const int qt = blockIdx.x;
    const int bh = blockIdx.y;
    const size_t base = (size_t)bh * SLEN * 64;
    const unsigned short* Qb = Q + base;
    const unsigned short* Kb = Kc + base;
    const unsigned short* Vb = Vt + base;        // [64][SLEN]
    const int q0 = qt * 64;
    const int qr = q0 + wid * 16;

    // Q fragments held in registers for the whole kernel
    s16x8 aq[2];
#pragma unroll
    for (int kk = 0; kk < 2; ++kk)
        aq[kk] = *reinterpret_cast<const s16x8*>(&Qb[(size_t)(qr + l15) * 64 + kk * 32 + 8 * lhi]);

    f32x4 o_acc[4];
#pragma unroll
    for (int nb = 0; nb < 4; ++nb) o_acc[nb] = (f32x4)0.f;
    float m_r[4], l_r[4];
#pragma unroll
    for (int r = 0; r < 4; ++r) { m_r[r] = -1e30f; l_r[r] = 0.f; }

    const int ntiles = qt + 1;   // causal: only kv tiles <= q tile
    for (int t = 0; t < ntiles; ++t) {
        const int kv0 = t * 64;
        // stage K tile [64][64] and V^T tile [64 d][64 kv]
#pragma unroll
        for (int p = 0; p < 2; ++p) {
            int idx = p * 256 + tid;
            int row = idx >> 3, c8 = (idx & 7) * 8;
            *reinterpret_cast<int4*>(&Ksm[row][c8]) =
                *reinterpret_cast<const int4*>(&Kb[(size_t)(kv0 + row) * 64 + c8]);
            *reinterpret_cast<int4*>(&Vsm[row][c8]) =
                *reinterpret_cast<const int4*>(&Vb[(size_t)row * SLEN + kv0 + c8]);
        }
        __syncthreads();

        // QK^T: scores [16 q][64 kv] per wave
        f32x4 sc[4];
#pragma unroll
        for (int nb = 0; nb < 4; ++nb) sc[nb] = (f32x4)0.f;
#pragma unroll
        for (int kk = 0; kk < 2; ++kk) {
            const int kc = kk * 32 + 8 * lhi;
#pragma unroll
            for (int nb = 0; nb < 4; ++nb) {
                s16x8 bk = *reinterpret_cast<const s16x8*>(&Ksm[nb * 16 + l15][kc]);
                sc[nb] = __builtin_amdgcn_mfma_f32_16x16x32_bf16(aq[kk], bk, sc[nb], 0, 0, 0);
            }
        }

        // scale + causal mask (diagonal tile only)
        float sv[4][4];
#pragma unroll
        for (int nb = 0; nb < 4; ++nb)
#pragma unroll
            for (int r = 0; r < 4; ++r) {
                float x = sc[nb][r] * 0.125f;
                if (t == qt) {
                    int col = kv0 + nb * 16 + l15;
                    int row = q0 + wid * 16 + lhi * 4 + r;
                    if (col > row) x = -1e30f;
                }
                sv[nb][r] = x;
            }

        // row max across 64 cols: reg-reduce over nb, lane-reduce over 16-lane group
        float tm[4];
#pragma unroll
        for (int r = 0; r < 4; ++r)
            tm[r] = fmaxf(fmaxf(sv[0][r], sv[1][r]), fmaxf(sv[2][r], sv[3][r]));
#pragma unroll
        for (int mask = 1; mask < 16; mask <<= 1)
#pragma unroll
            for (int r = 0; r < 4; ++r)
                tm[r] = fmaxf(tm[r], __shfl_xor(tm[r], mask, 64));

        float alpha[4], rs[4];
#pragma unroll
        for (int r = 0; r < 4; ++r) {
            float mn = fmaxf(m_r[r], tm[r]);
            alpha[r] = __expf(m_r[r] - mn);
            m_r[r] = mn;
            rs[r] = 0.f;
        }
        float pv[4][4];
#pragma unroll
        for (int nb = 0; nb < 4; ++nb)
#pragma unroll
            for (int r = 0; r < 4; ++r) {
                float p = __expf(sv[nb][r] - m_r[r]);
                pv[nb][r] = p;
                rs[r] += p;
            }
#pragma unroll
        for (int mask = 1; mask < 16; mask <<= 1)
#pragma unroll
            for (int r = 0; r < 4; ++r)
                rs[r] += __shfl_xor(rs[r], mask, 64);
#pragma unroll
        for (int r = 0; r < 4; ++r) l_r[r] = l_r[r] * alpha[r] + rs[r];
#pragma unroll
        for (int nb = 0; nb < 4; ++nb)
#pragma unroll
            for (int r = 0; r < 4; ++r) o_acc[nb][r] *= alpha[r];

        // P -> bf16 via per-wave LDS (re-shape to MFMA A-fragment layout)
#pragma unroll
        for (int nb = 0; nb < 4; ++nb)
#pragma unroll
            for (int r = 0; r < 4; ++r)
                Psm[wid][lhi * 4 + r][nb * 16 + l15] = f2bf(pv[nb][r]);
        // wave-local LDS RAW: compiler inserts lgkmcnt waits; no barrier needed.

        // PV: o += P @ V   (B-operand from V^T tile, contiguous along kv)
#pragma unroll
        for (int kk = 0; kk < 2; ++kk) {
            const int kc = kk * 32 + 8 * lhi;
            s16x8 pa = *reinterpret_cast<const s16x8*>(&Psm[wid][l15][kc]);
#pragma unroll
            for (int nb = 0; nb < 4; ++nb) {
                s16x8 bv = *reinterpret_cast<const s16x8*>(&Vsm[nb * 16 + l15][kc]);
                o_acc[nb] = __builtin_amdgcn_mfma_f32_16x16x32_bf16(pa, bv, o_acc[nb], 0, 0, 0);
            }
        }
        __syncthreads();   // protect Ksm/Vsm before next stage
    }

    // epilogue: out[b, s, h*64+d] = o/l
    const int b = bh >> 4, h = bh & 15;
#pragma unroll
    for (int nb = 0; nb < 4; ++nb)
#pragma unroll
        for (int r = 0; r < 4; ++r) {
            const int s = q0 + wid * 16 + lhi * 4 + r;
            const float val = o_acc[nb][r] / l_r[r];
            Ao[((size_t)b * SLEN + s) * DMOD + h * 64 + nb * 16 + l15] = f2bf(val);
        }
}

extern "C" void kernel_launch(void* const* d_in, const int* in_sizes, int n_in,
                              void* d_out, int out_size, void* d_ws, size_t ws_size,
                              hipStream_t stream) {
    const float* q  = (const float*)d_in[0];
    const float* k  = (const float*)d_in[1];
    const float* v  = (const float*)d_in[2];
    // d_in[3] = mask: tril causal, handled structurally (never read)
    const float* Wq = (const float*)d_in[4];
    const float* bq = (const float*)d_in[5];
    const float* Wk = (const float*)d_in[6];
    const float* bk = (const float*)d_in[7];
    const float* Wv = (const float*)d_in[8];
    const float* bv = (const float*)d_in[9];
    const float* Wo = (const float*)d_in[10];
    const float* bo = (const float*)d_in[11];

    // workspace: 4 x 16.8MB bf16 buffers = 67.1 MB
    unsigned short* qb  = (unsigned short*)d_ws;
    unsigned short* kb  = qb + 8388608;
    unsigned short* vtb = kb + 8388608;
    unsigned short* ao  = vtb + 8388608;

    dim3 gg(8, 64), gb(256);
    proj_gemm<0, false><<<gg, gb, 0, stream>>>(q, Wq, bq, qb);
    proj_gemm<0, false><<<gg, gb, 0, stream>>>(k, Wk, bk, kb);
    proj_gemm<1, false><<<gg, gb, 0, stream>>>(v, Wv, bv, vtb);
    attn_kernel<<<dim3(32, 64), gb, 0, stream>>>(qb, kb, vtb, ao);
    proj_gemm<2, true><<<gg, gb, 0, stream>>>(ao, Wo, bo, (float*)d_out);
}